// Round 13
// baseline (135.406 us; speedup 1.0000x reference)
//
#include <hip/hip_runtime.h>
#include <cstdint>

typedef _Float16 f16x8 __attribute__((ext_vector_type(8)));
typedef float f32x4 __attribute__((ext_vector_type(4)));
typedef _Float16 half2_t __attribute__((ext_vector_type(2)));

__device__ __forceinline__ unsigned pkh2(float a, float b) {
  return __builtin_bit_cast(unsigned, __builtin_amdgcn_cvt_pkrtz(a, b));
}
__device__ __forceinline__ float fast_tanh(float x) {
  float e = __builtin_amdgcn_exp2f(x * 2.885390081777927f);
  return 1.0f - 2.0f * __builtin_amdgcn_rcpf(e + 1.0f);
}

#if __has_builtin(__builtin_amdgcn_fdot2)
__device__ __forceinline__ float dot2h(unsigned a, unsigned b, float c) {
  return __builtin_amdgcn_fdot2(__builtin_bit_cast(half2_t, a),
                                __builtin_bit_cast(half2_t, b), c, false);
}
#else
__device__ __forceinline__ float dot2h(unsigned a, unsigned b, float c) {
  float d;
  asm("v_dot2_f32_f16 %0, %1, %2, %3" : "=v"(d) : "v"(a), "v"(b), "v"(c));
  return d;
}
#endif

// ---------------------------------------------------------------------------
// Stage 1 (r8-verified, byte-identical): per-(ks,bt,co) partial GEMM via
// fp16 MFMA. Epilogue -> co-major part[ks][bt][co][pos].
// ---------------------------------------------------------------------------
template <int ITERS>
__global__ __launch_bounds__(256, 2) void k_stage1(const float* __restrict__ x,
                                                   const float* __restrict__ w1,
                                                   const float* __restrict__ w3,
                                                   float* __restrict__ part,
                                                   unsigned* __restrict__ wtab) {
  constexpr int NS = 32 / ITERS;  // K-split count
  constexpr int KSB = (NS == 8) ? 3 : (NS == 4) ? 2 : (NS == 2) ? 1 : 0;
  __shared__ __align__(16) char lds_raw[64 * 65 * 4];      // 16640 B
  unsigned short* As = (unsigned short*)lds_raw;           // 64 rows * 40 hw
  unsigned short* Bs = (unsigned short*)(lds_raw + 5120);  // 64 rows * 40 hw
  float* Cs = (float*)lds_raw;                             // 64 x 65 fp32

  const int tid = threadIdx.x;
  if (blockIdx.x == 0) {  // legacy wtab pack (unused by stage23 now; harmless)
    int l = tid << 2;
#pragma unroll
    for (int j = 0; j < 4; ++j) {
      int d = l + j;
      int slot = d & 3, chU = (d >> 2) & 1, kh = (d >> 3) & 3,
          kd = (d >> 5) & 3, cio = d >> 7;
      int co = (chU << 1) + (slot & 1);
      int kwb = (slot >> 1) << 1;
      int base = ((co << 3) + cio) * 64 + (kd << 4) + (kh << 2) + kwb;
      wtab[d] = pkh2(w3[base], w3[base + 1]);
    }
  }

  const int ks = blockIdx.x & (NS - 1);
  const int bt = (blockIdx.x >> KSB) & 15;
  const int co = blockIdx.x >> (KSB + 4);
  const int w = tid >> 6, lane = tid & 63, lm = lane & 15, q = lane >> 4;
  const int rrow = tid & 63, kgr = tid >> 6;

  f32x4 acc[4];
#pragma unroll
  for (int i = 0; i < 4; ++i) acc[i] = (f32x4){0.f, 0.f, 0.f, 0.f};

  const float* gA = x + (bt << 16) + ((size_t)(ks * ITERS * 32) << 6);
  const float* gB = w1 + (co << 6) + (size_t)(ks * ITERS * 32) * 512;

  float va[2][8], vb[2][8];
#define S1_LOAD(buf, it)                            \
  {                                                 \
    const int kb = (it) * 32 + (kgr << 3);          \
    _Pragma("unroll") for (int j = 0; j < 8; ++j) { \
      va[buf][j] = gA[((kb + j) << 6) | rrow];      \
      vb[buf][j] = gB[(kb + j) * 512 + rrow];       \
    }                                               \
  }
  S1_LOAD(0, 0);
#pragma unroll
  for (int it = 0; it < ITERS; ++it) {
    const int cur = it & 1;
    if (it + 1 < ITERS) S1_LOAD(cur ^ 1, it + 1);
    uint4 pa, pb;
    pa.x = pkh2(va[cur][0], va[cur][1]);
    pa.y = pkh2(va[cur][2], va[cur][3]);
    pa.z = pkh2(va[cur][4], va[cur][5]);
    pa.w = pkh2(va[cur][6], va[cur][7]);
    pb.x = pkh2(vb[cur][0], vb[cur][1]);
    pb.y = pkh2(vb[cur][2], vb[cur][3]);
    pb.z = pkh2(vb[cur][4], vb[cur][5]);
    pb.w = pkh2(vb[cur][6], vb[cur][7]);
    *(uint4*)&As[rrow * 40 + (kgr << 3)] = pa;
    *(uint4*)&Bs[rrow * 40 + (kgr << 3)] = pb;
    __syncthreads();
    f16x8 a = *(const f16x8*)&As[((w << 4) + lm) * 40 + (q << 3)];
#pragma unroll
    for (int nf = 0; nf < 4; ++nf) {
      f16x8 b = *(const f16x8*)&Bs[((nf << 4) + lm) * 40 + (q << 3)];
      acc[nf] = __builtin_amdgcn_mfma_f32_16x16x32_f16(a, b, acc[nf], 0, 0, 0);
    }
    __syncthreads();
  }
#undef S1_LOAD
#pragma unroll
  for (int nf = 0; nf < 4; ++nf)
#pragma unroll
    for (int r = 0; r < 4; ++r) {
      int m = (w << 4) + (q << 2) + r;
      int n = (nf << 4) + lm;
      Cs[m * 65 + n] = acc[nf][r];
    }
  __syncthreads();
  float* dst = part + (((size_t)(((ks << 4) + bt) << 3) + co) << 12);
#pragma unroll
  for (int j = 0; j < 4; ++j) {
    int pos = (tid << 2) + (j << 10);
    int z = pos >> 8, y = (pos >> 4) & 15, xx = pos & 15;
    int m = ((z >> 2) << 4) + ((y >> 2) << 2) + (xx >> 2);
    int n = ((z & 3) << 4) + ((y & 3) << 2);
    float4 v;
    v.x = Cs[m * 65 + n + 0];
    v.y = Cs[m * 65 + n + 1];
    v.z = Cs[m * 65 + n + 2];
    v.w = Cs[m * 65 + n + 3];
    *(float4*)&dst[pos] = v;
  }
}

// ---------------------------------------------------------------------------
// Fused stage 2+3, r13 MFMA-conv rewrite. 512 thr, 1024 blocks.
// Out tile z8 y8 x8 (64 tiles x 16 bt). Window = 18^3 CELLS of [ci8] fp16
// (16B each, 93KB): cell (wz,wy,wx) holds h2 for all 8 cio -> it IS an MFMA
// A-fragment b128. Two phases, TWO barriers total:
//   [stage h1p,w2p,w3p] bar [fill all cells x 8 cio] bar [MFMA conv + store]
// Conv: D[pos16][co16] += A[pos16][K32] * B[co16][K32], K = kw(4)x cio(8),
// iterated over 16 (kd,kh). Lane maps mirrored from stage1's verified GEMM:
//   A row = lane&15 (pos = yy*8+x), A k = (lane>>4)*8+j -> kw=lane>>4, cio=j
//   B row = lane&15 (co, >=4 zero-padded), same k
//   D m = (lane>>4)*4+r (pos), n = lane&15 (co)  -> lanes n<4 store.
// Replaces 2048 serial dot2/thread with ~64 MFMA + 80 ds_read per WAVE.
// Fill vals/thread drop 172 -> ~91 (18^3 window serves this tile only).
// XCD: bid%8 = (ty&1)*4+tx -> all bt of a tile colocate (out-line assembly).
// ---------------------------------------------------------------------------
template <int NSPLIT>
__global__ __launch_bounds__(512) void k_stage23(
    const float* __restrict__ part, const float* __restrict__ w2,
    const float* __restrict__ b2, const float* __restrict__ b3,
    const float* __restrict__ b1, const float* __restrict__ w3,
    float* __restrict__ out) {
  __shared__ __align__(16) unsigned win[18 * 18 * 18 * 4];  // 93312 B
  __shared__ __align__(16) unsigned h1p[216 * 4];           // 3456 B
  __shared__ __align__(16) unsigned w2p[8 * 320];           // 10240 B
  __shared__ __align__(16) unsigned w3p[16 * 64 * 4];       // 16384 B

  const int tid = threadIdx.x;
  const int bid = blockIdx.x;
  const int tile = bid & 63;  // bid%8 = (ty&1)<<2 | tx -> XCD colocation
  const int bt = bid >> 6;
  const int tz = tile >> 4, ty = (tile >> 2) & 3, tx = tile & 3;
  const int Z0 = tz << 3, Y0 = ty << 3, X0 = tx << 3;
  const int Qz0 = (Z0 << 1) - 1, Qy0 = (Y0 << 1) - 1, Qx0 = (X0 << 1) - 1;
  const int Uz0 = Qz0 >> 2, Uy0 = Qy0 >> 2, Ux0 = Qx0 >> 2;

  // ---- staging: h1 = tanh(sum_s part + b1) -> h1p cells [uz][uy][ux][ci8]
  // 6x6x6 u-cells x 8 ci = 1728 fp16. ci-outer => coalesced part reads.
#pragma unroll
  for (int k = 0; k < 4; ++k) {
    int l = tid + (k << 9);
    bool vld = l < 1728;
    int ll = vld ? l : 0;
    int ci = ll / 216;
    int sp = ll - ci * 216;
    int uz = sp / 36;
    int t1 = sp - uz * 36;
    int uy = t1 / 6;
    int ux = t1 - uy * 6;
    int gz = Uz0 + uz, gy = Uy0 + uy, gx = Ux0 + ux;
    bool inb = vld && (unsigned)gz < 16u && (unsigned)gy < 16u &&
               (unsigned)gx < 16u;
    float v = 0.f;
    if (inb) {
      const float* p =
          part + (((size_t)(bt << 3) + ci) << 12) + (gz << 8) + (gy << 4) + gx;
      float s = b1[ci];
#pragma unroll
      for (int sg = 0; sg < NSPLIT; ++sg) s += p[(size_t)sg << 19];
      v = fast_tanh(s);
    }
    if (vld)
      ((_Float16*)h1p)[(((uz * 6 + uy) * 6 + ux) << 3) + ci] = (_Float16)v;
  }

  // ---- w2 pack (unchanged layout): dword = [cio][kzy stride20][kx*4+j]
  for (int l = tid; l < 2048; l += 512) {
    int j = l & 3, kx = (l >> 2) & 3, kzy = (l >> 4) & 15, cio = l >> 8;
    int kpos = (kzy << 2) + kx;
    float w0 = w2[(((j << 1) << 3) + cio) * 64 + kpos];
    float w1v = w2[((((j << 1) + 1) << 3) + cio) * 64 + kpos];
    w2p[cio * 320 + kzy * 20 + (kx << 2) + j] = pkh2(w0, w1v);
  }

  // ---- w3 MFMA B-fragment pack: slot s = [kdkh 16][lane 64] of 8 fp16:
  // co = lane&15 (>=4 -> zeros), kw = lane>>4, halves j = cio 0..7.
  for (int l = tid; l < 1024; l += 512) {
    int kdkh = l >> 6, lane = l & 63;
    int co = lane & 15, kw = lane >> 4;
    int kd = kdkh >> 2, kh = kdkh & 3;
    uint4 v;
    v.x = v.y = v.z = v.w = 0u;
    if (co < 4) {
      int base = (co << 3) * 64 + (kd << 4) + (kh << 2) + kw;  // cio stride 64
      v.x = pkh2(w3[base], w3[base + 64]);
      v.y = pkh2(w3[base + 128], w3[base + 192]);
      v.z = pkh2(w3[base + 256], w3[base + 320]);
      v.w = pkh2(w3[base + 384], w3[base + 448]);
    }
    *(uint4*)&w3p[l << 2] = v;
  }

  // ---- fill-cell precompute: 5832 cells, up to 12 per thread
  int f_win[12], f_h1[12], f_w2[12];
  bool f_act[12];
#pragma unroll
  for (int k = 0; k < 12; ++k) {
    int c = tid + (k << 9);
    bool vld = c < 5832;
    int cc = vld ? c : 0;
    int wz = cc / 324;
    int r2 = cc - wz * 324;
    int wy = r2 / 18;
    int wx = r2 - wy * 18;
    int qz = Qz0 + wz, qy = Qy0 + wy, qx = Qx0 + wx;
    f_act[k] = vld && (unsigned)qz < 64u && (unsigned)qy < 64u &&
               (unsigned)qx < 64u;
    f_win[k] = vld ? (((wz * 18 + wy) * 18 + wx) << 2) : -1;
    int kzy = ((qz & 3) << 2) | (qy & 3);
    f_w2[k] = kzy * 20 + ((qx & 3) << 2);
    f_h1[k] = ((((qz >> 2) - Uz0) * 6 + ((qy >> 2) - Uy0)) * 6 +
               ((qx >> 2) - Ux0))
              << 2;
  }
  float b2v[8];
#pragma unroll
  for (int c = 0; c < 8; ++c) b2v[c] = b2[c];

  __syncthreads();  // staging + packs visible

  // ---- fill: every window cell = 8 cio h2 values (fp16), OOB -> zeros
#pragma unroll
  for (int k = 0; k < 12; ++k) {
    int wo = f_win[k];
    if (wo < 0) continue;
    uint4 sv;
    sv.x = sv.y = sv.z = sv.w = 0u;
    if (f_act[k]) {
      uint4 h = *(const uint4*)&h1p[f_h1[k]];
      float vals[8];
#pragma unroll
      for (int cio = 0; cio < 8; ++cio) {
        uint4 wv = *(const uint4*)&w2p[cio * 320 + f_w2[k]];
        vals[cio] = fast_tanh(
            dot2h(h.w, wv.w,
                  dot2h(h.z, wv.z,
                        dot2h(h.y, wv.y, dot2h(h.x, wv.x, b2v[cio])))));
      }
      sv.x = pkh2(vals[0], vals[1]);
      sv.y = pkh2(vals[2], vals[3]);
      sv.z = pkh2(vals[4], vals[5]);
      sv.w = pkh2(vals[6], vals[7]);
    }
    *(uint4*)&win[wo] = sv;
  }
  __syncthreads();  // window complete

  // ---- conv: MFMA. wave handles 4 M-tiles (id = i*8+wave: zq=id>>2, yp=id&3)
  const int wave = tid >> 6, lane = tid & 63;
  const int n = lane & 15, q = lane >> 4;        // D col (co), kw / D row-blk
  const int yy = (lane & 15) >> 3, xl = lane & 7;  // A row -> pos (yy,x)
  f32x4 acc[4];
  int celloff[4];
#pragma unroll
  for (int i = 0; i < 4; ++i) {
    acc[i] = (f32x4){0.f, 0.f, 0.f, 0.f};
    int id = (i << 3) + wave;
    int zq = id >> 2, yp = id & 3;
    celloff[i] =
        ((((zq << 1) * 18 + (yp << 2) + (yy << 1)) * 18 + (xl << 1) + q) << 2);
  }
#pragma unroll
  for (int kd = 0; kd < 4; ++kd) {
#pragma unroll
    for (int kh = 0; kh < 4; ++kh) {
      f16x8 B = *(const f16x8*)&w3p[((((kd << 2) + kh) << 6) | lane) << 2];
      const int koff = (kd * 324 + kh * 18) << 2;
#pragma unroll
      for (int i = 0; i < 4; ++i) {
        f16x8 A = *(const f16x8*)&win[celloff[i] + koff];
        acc[i] = __builtin_amdgcn_mfma_f32_16x16x32_f16(A, B, acc[i], 0, 0, 0);
      }
    }
  }

  // ---- epilogue: lanes n<4 hold co=n; rows m = q*4+r -> pos (yy2, x2)
  if (n < 4) {
    const float bias = b3[n];
    const int b = bt >> 3, t8 = bt & 7;
#pragma unroll
    for (int i = 0; i < 4; ++i) {
      int id = (i << 3) + wave;
      int zq = id >> 2, yp = id & 3;
      int z = Z0 + zq;
#pragma unroll
      for (int r = 0; r < 4; ++r) {
        int m = (q << 2) + r;
        int yy2 = m >> 3, x2 = m & 7;
        int y = Y0 + (yp << 1) + yy2;
        int xx = X0 + x2;
        out[(((((b << 2) + n) * 32 + z) * 32 + y) * 32 + xx) << 3 | t8] =
            acc[i][r] + bias;
      }
    }
  }
}

extern "C" void kernel_launch(void* const* d_in, const int* in_sizes, int n_in,
                              void* d_out, int out_size, void* d_ws,
                              size_t ws_size, hipStream_t stream) {
  (void)in_sizes; (void)n_in; (void)out_size;
  const float* x = (const float*)d_in[0];
  const float* w1 = (const float*)d_in[1];
  const float* b1 = (const float*)d_in[2];
  const float* w2 = (const float*)d_in[3];
  const float* b2 = (const float*)d_in[4];
  const float* w3 = (const float*)d_in[5];
  const float* b3 = (const float*)d_in[6];
  float* out = (float*)d_out;
  float* part = (float*)d_ws;

  const size_t plane = (size_t)16 * 8 * 4096;  // floats per split (2 MB)
  int nsplit = 1;
  if (ws_size >= 4 * plane * 4 + 4096)
    nsplit = 4;
  else if (ws_size >= 2 * plane * 4 + 4096)
    nsplit = 2;
  unsigned* wtab = (unsigned*)(part + (size_t)nsplit * plane);

  switch (nsplit) {
    case 4:
      k_stage1<8><<<dim3(512), dim3(256), 0, stream>>>(x, w1, w3, part, wtab);
      k_stage23<4><<<dim3(1024), dim3(512), 0, stream>>>(part, w2, b2, b3, b1,
                                                         w3, out);
      break;
    case 2:
      k_stage1<16><<<dim3(256), dim3(256), 0, stream>>>(x, w1, w3, part, wtab);
      k_stage23<2><<<dim3(1024), dim3(512), 0, stream>>>(part, w2, b2, b3, b1,
                                                         w3, out);
      break;
    default:
      k_stage1<32><<<dim3(128), dim3(256), 0, stream>>>(x, w1, w3, part, wtab);
      k_stage23<1><<<dim3(1024), dim3(512), 0, stream>>>(part, w2, b2, b3, b1,
                                                         w3, out);
      break;
  }
}

// Round 14
// 131.338 us; speedup vs baseline: 1.0310x; 1.0310x over previous
//
#include <hip/hip_runtime.h>
#include <cstdint>

typedef _Float16 f16x8 __attribute__((ext_vector_type(8)));
typedef float f32x4 __attribute__((ext_vector_type(4)));
typedef _Float16 half2_t __attribute__((ext_vector_type(2)));

__device__ __forceinline__ unsigned pkh2(float a, float b) {
  return __builtin_bit_cast(unsigned, __builtin_amdgcn_cvt_pkrtz(a, b));
}
__device__ __forceinline__ float fast_tanh(float x) {
  float e = __builtin_amdgcn_exp2f(x * 2.885390081777927f);
  return 1.0f - 2.0f * __builtin_amdgcn_rcpf(e + 1.0f);
}

#if __has_builtin(__builtin_amdgcn_fdot2)
__device__ __forceinline__ float dot2h(unsigned a, unsigned b, float c) {
  return __builtin_amdgcn_fdot2(__builtin_bit_cast(half2_t, a),
                                __builtin_bit_cast(half2_t, b), c, false);
}
#else
__device__ __forceinline__ float dot2h(unsigned a, unsigned b, float c) {
  float d;
  asm("v_dot2_f32_f16 %0, %1, %2, %3" : "=v"(d) : "v"(a), "v"(b), "v"(c));
  return d;
}
#endif

// ---------------------------------------------------------------------------
// Stage 1 (r8-verified, byte-identical): per-(ks,bt,co) partial GEMM via
// fp16 MFMA. Epilogue -> co-major part[ks][bt][co][pos].
// ---------------------------------------------------------------------------
template <int ITERS>
__global__ __launch_bounds__(256, 2) void k_stage1(const float* __restrict__ x,
                                                   const float* __restrict__ w1,
                                                   const float* __restrict__ w3,
                                                   float* __restrict__ part,
                                                   unsigned* __restrict__ wtab) {
  constexpr int NS = 32 / ITERS;  // K-split count
  constexpr int KSB = (NS == 8) ? 3 : (NS == 4) ? 2 : (NS == 2) ? 1 : 0;
  __shared__ __align__(16) char lds_raw[64 * 65 * 4];      // 16640 B
  unsigned short* As = (unsigned short*)lds_raw;           // 64 rows * 40 hw
  unsigned short* Bs = (unsigned short*)(lds_raw + 5120);  // 64 rows * 40 hw
  float* Cs = (float*)lds_raw;                             // 64 x 65 fp32

  const int tid = threadIdx.x;
  if (blockIdx.x == 0) {  // legacy wtab pack (unused by stage23 now; harmless)
    int l = tid << 2;
#pragma unroll
    for (int j = 0; j < 4; ++j) {
      int d = l + j;
      int slot = d & 3, chU = (d >> 2) & 1, kh = (d >> 3) & 3,
          kd = (d >> 5) & 3, cio = d >> 7;
      int co = (chU << 1) + (slot & 1);
      int kwb = (slot >> 1) << 1;
      int base = ((co << 3) + cio) * 64 + (kd << 4) + (kh << 2) + kwb;
      wtab[d] = pkh2(w3[base], w3[base + 1]);
    }
  }

  const int ks = blockIdx.x & (NS - 1);
  const int bt = (blockIdx.x >> KSB) & 15;
  const int co = blockIdx.x >> (KSB + 4);
  const int w = tid >> 6, lane = tid & 63, lm = lane & 15, q = lane >> 4;
  const int rrow = tid & 63, kgr = tid >> 6;

  f32x4 acc[4];
#pragma unroll
  for (int i = 0; i < 4; ++i) acc[i] = (f32x4){0.f, 0.f, 0.f, 0.f};

  const float* gA = x + (bt << 16) + ((size_t)(ks * ITERS * 32) << 6);
  const float* gB = w1 + (co << 6) + (size_t)(ks * ITERS * 32) * 512;

  float va[2][8], vb[2][8];
#define S1_LOAD(buf, it)                            \
  {                                                 \
    const int kb = (it) * 32 + (kgr << 3);          \
    _Pragma("unroll") for (int j = 0; j < 8; ++j) { \
      va[buf][j] = gA[((kb + j) << 6) | rrow];      \
      vb[buf][j] = gB[(kb + j) * 512 + rrow];       \
    }                                               \
  }
  S1_LOAD(0, 0);
#pragma unroll
  for (int it = 0; it < ITERS; ++it) {
    const int cur = it & 1;
    if (it + 1 < ITERS) S1_LOAD(cur ^ 1, it + 1);
    uint4 pa, pb;
    pa.x = pkh2(va[cur][0], va[cur][1]);
    pa.y = pkh2(va[cur][2], va[cur][3]);
    pa.z = pkh2(va[cur][4], va[cur][5]);
    pa.w = pkh2(va[cur][6], va[cur][7]);
    pb.x = pkh2(vb[cur][0], vb[cur][1]);
    pb.y = pkh2(vb[cur][2], vb[cur][3]);
    pb.z = pkh2(vb[cur][4], vb[cur][5]);
    pb.w = pkh2(vb[cur][6], vb[cur][7]);
    *(uint4*)&As[rrow * 40 + (kgr << 3)] = pa;
    *(uint4*)&Bs[rrow * 40 + (kgr << 3)] = pb;
    __syncthreads();
    f16x8 a = *(const f16x8*)&As[((w << 4) + lm) * 40 + (q << 3)];
#pragma unroll
    for (int nf = 0; nf < 4; ++nf) {
      f16x8 b = *(const f16x8*)&Bs[((nf << 4) + lm) * 40 + (q << 3)];
      acc[nf] = __builtin_amdgcn_mfma_f32_16x16x32_f16(a, b, acc[nf], 0, 0, 0);
    }
    __syncthreads();
  }
#undef S1_LOAD
#pragma unroll
  for (int nf = 0; nf < 4; ++nf)
#pragma unroll
    for (int r = 0; r < 4; ++r) {
      int m = (w << 4) + (q << 2) + r;
      int n = (nf << 4) + lm;
      Cs[m * 65 + n] = acc[nf][r];
    }
  __syncthreads();
  float* dst = part + (((size_t)(((ks << 4) + bt) << 3) + co) << 12);
#pragma unroll
  for (int j = 0; j < 4; ++j) {
    int pos = (tid << 2) + (j << 10);
    int z = pos >> 8, y = (pos >> 4) & 15, xx = pos & 15;
    int m = ((z >> 2) << 4) + ((y >> 2) << 2) + (xx >> 2);
    int n = ((z & 3) << 4) + ((y & 3) << 2);
    float4 v;
    v.x = Cs[m * 65 + n + 0];
    v.y = Cs[m * 65 + n + 1];
    v.z = Cs[m * 65 + n + 2];
    v.w = Cs[m * 65 + n + 3];
    *(float4*)&dst[pos] = v;
  }
}

// ---------------------------------------------------------------------------
// Fused stage 2+3, r14 = r13 MFMA-conv kernel at 1024 THREADS.
// r13 ran 512 thr with LDS 123KB -> 1 block/CU = 2 waves/SIMD: fill phase
// (same ~47M dot2+tanh total as r12) had no latency hiding -> 67us.
// 1024 thr keeps LDS/dataflow identical but gives 16 waves/block =
// 4 waves/SIMD (r12's proven level) and halves per-thread fill (12->6).
// Two barriers total: [stage] bar [fill] bar [MFMA conv + store].
// Lane maps and layouts byte-identical to the r13-verified kernel.
// ---------------------------------------------------------------------------
template <int NSPLIT>
__global__ __launch_bounds__(1024) void k_stage23(
    const float* __restrict__ part, const float* __restrict__ w2,
    const float* __restrict__ b2, const float* __restrict__ b3,
    const float* __restrict__ b1, const float* __restrict__ w3,
    float* __restrict__ out) {
  __shared__ __align__(16) unsigned win[18 * 18 * 18 * 4];  // 93312 B
  __shared__ __align__(16) unsigned h1p[216 * 4];           // 3456 B
  __shared__ __align__(16) unsigned w2p[8 * 320];           // 10240 B
  __shared__ __align__(16) unsigned w3p[16 * 64 * 4];       // 16384 B

  const int tid = threadIdx.x;
  const int bid = blockIdx.x;
  const int tile = bid & 63;  // bid%8 = (ty&1)<<2 | tx -> XCD colocation
  const int bt = bid >> 6;
  const int tz = tile >> 4, ty = (tile >> 2) & 3, tx = tile & 3;
  const int Z0 = tz << 3, Y0 = ty << 3, X0 = tx << 3;
  const int Qz0 = (Z0 << 1) - 1, Qy0 = (Y0 << 1) - 1, Qx0 = (X0 << 1) - 1;
  const int Uz0 = Qz0 >> 2, Uy0 = Qy0 >> 2, Ux0 = Qx0 >> 2;

  // ---- staging: h1 = tanh(sum_s part + b1) -> h1p cells [uz][uy][ux][ci8]
#pragma unroll
  for (int k = 0; k < 2; ++k) {
    int l = tid + (k << 10);
    bool vld = l < 1728;
    int ll = vld ? l : 0;
    int ci = ll / 216;
    int sp = ll - ci * 216;
    int uz = sp / 36;
    int t1 = sp - uz * 36;
    int uy = t1 / 6;
    int ux = t1 - uy * 6;
    int gz = Uz0 + uz, gy = Uy0 + uy, gx = Ux0 + ux;
    bool inb = vld && (unsigned)gz < 16u && (unsigned)gy < 16u &&
               (unsigned)gx < 16u;
    float v = 0.f;
    if (inb) {
      const float* p =
          part + (((size_t)(bt << 3) + ci) << 12) + (gz << 8) + (gy << 4) + gx;
      float s = b1[ci];
#pragma unroll
      for (int sg = 0; sg < NSPLIT; ++sg) s += p[(size_t)sg << 19];
      v = fast_tanh(s);
    }
    if (vld)
      ((_Float16*)h1p)[(((uz * 6 + uy) * 6 + ux) << 3) + ci] = (_Float16)v;
  }

  // ---- w2 pack: dword = [cio][kzy stride20][kx*4+j]
  for (int l = tid; l < 2048; l += 1024) {
    int j = l & 3, kx = (l >> 2) & 3, kzy = (l >> 4) & 15, cio = l >> 8;
    int kpos = (kzy << 2) + kx;
    float w0 = w2[(((j << 1) << 3) + cio) * 64 + kpos];
    float w1v = w2[((((j << 1) + 1) << 3) + cio) * 64 + kpos];
    w2p[cio * 320 + kzy * 20 + (kx << 2) + j] = pkh2(w0, w1v);
  }

  // ---- w3 MFMA B-fragment pack: slot = [kdkh 16][lane 64] of 8 fp16:
  // co = lane&15 (>=4 -> zeros), kw = lane>>4, halves j = cio 0..7.
  if (tid < 1024) {
    int l = tid;
    int lane = l & 63;
    int kdkh = l >> 6;
    int co = lane & 15, kw = lane >> 4;
    int kd = kdkh >> 2, kh = kdkh & 3;
    uint4 v;
    v.x = v.y = v.z = v.w = 0u;
    if (co < 4) {
      int base = (co << 3) * 64 + (kd << 4) + (kh << 2) + kw;  // cio stride 64
      v.x = pkh2(w3[base], w3[base + 64]);
      v.y = pkh2(w3[base + 128], w3[base + 192]);
      v.z = pkh2(w3[base + 256], w3[base + 320]);
      v.w = pkh2(w3[base + 384], w3[base + 448]);
    }
    *(uint4*)&w3p[l << 2] = v;
  }

  // ---- fill-cell precompute: 5832 cells, up to 6 per thread
  int f_win[6], f_h1[6], f_w2[6];
  bool f_act[6];
#pragma unroll
  for (int k = 0; k < 6; ++k) {
    int c = tid + (k << 10);
    bool vld = c < 5832;
    int cc = vld ? c : 0;
    int wz = cc / 324;
    int r2 = cc - wz * 324;
    int wy = r2 / 18;
    int wx = r2 - wy * 18;
    int qz = Qz0 + wz, qy = Qy0 + wy, qx = Qx0 + wx;
    f_act[k] = vld && (unsigned)qz < 64u && (unsigned)qy < 64u &&
               (unsigned)qx < 64u;
    f_win[k] = vld ? (((wz * 18 + wy) * 18 + wx) << 2) : -1;
    int kzy = ((qz & 3) << 2) | (qy & 3);
    f_w2[k] = kzy * 20 + ((qx & 3) << 2);
    f_h1[k] = ((((qz >> 2) - Uz0) * 6 + ((qy >> 2) - Uy0)) * 6 +
               ((qx >> 2) - Ux0))
              << 2;
  }
  float b2v[8];
#pragma unroll
  for (int c = 0; c < 8; ++c) b2v[c] = b2[c];

  __syncthreads();  // staging + packs visible

  // ---- fill: every window cell = 8 cio h2 values (fp16), OOB -> zeros
#pragma unroll
  for (int k = 0; k < 6; ++k) {
    int wo = f_win[k];
    if (wo < 0) continue;
    uint4 sv;
    sv.x = sv.y = sv.z = sv.w = 0u;
    if (f_act[k]) {
      uint4 h = *(const uint4*)&h1p[f_h1[k]];
      float vals[8];
#pragma unroll
      for (int cio = 0; cio < 8; ++cio) {
        uint4 wv = *(const uint4*)&w2p[cio * 320 + f_w2[k]];
        vals[cio] = fast_tanh(
            dot2h(h.w, wv.w,
                  dot2h(h.z, wv.z,
                        dot2h(h.y, wv.y, dot2h(h.x, wv.x, b2v[cio])))));
      }
      sv.x = pkh2(vals[0], vals[1]);
      sv.y = pkh2(vals[2], vals[3]);
      sv.z = pkh2(vals[4], vals[5]);
      sv.w = pkh2(vals[6], vals[7]);
    }
    *(uint4*)&win[wo] = sv;
  }
  __syncthreads();  // window complete

  // ---- conv: MFMA. 16 waves; wave handles 2 M-tiles (id = i*16 + wave)
  const int wave = tid >> 6, lane = tid & 63;
  const int n = lane & 15, q = lane >> 4;          // D col (co), kw/row-blk
  const int yy = (lane & 15) >> 3, xl = lane & 7;  // A row -> pos (yy,x)
  f32x4 acc[2];
  int celloff[2];
#pragma unroll
  for (int i = 0; i < 2; ++i) {
    acc[i] = (f32x4){0.f, 0.f, 0.f, 0.f};
    int id = (i << 4) + wave;
    int zq = id >> 2, yp = id & 3;
    celloff[i] =
        ((((zq << 1) * 18 + (yp << 2) + (yy << 1)) * 18 + (xl << 1) + q) << 2);
  }
#pragma unroll
  for (int kd = 0; kd < 4; ++kd) {
#pragma unroll
    for (int kh = 0; kh < 4; ++kh) {
      f16x8 B = *(const f16x8*)&w3p[((((kd << 2) + kh) << 6) | lane) << 2];
      const int koff = (kd * 324 + kh * 18) << 2;
#pragma unroll
      for (int i = 0; i < 2; ++i) {
        f16x8 A = *(const f16x8*)&win[celloff[i] + koff];
        acc[i] = __builtin_amdgcn_mfma_f32_16x16x32_f16(A, B, acc[i], 0, 0, 0);
      }
    }
  }

  // ---- epilogue: lanes n<4 hold co=n; rows m = q*4+r -> pos (yy2, x2)
  if (n < 4) {
    const float bias = b3[n];
    const int b = bt >> 3, t8 = bt & 7;
#pragma unroll
    for (int i = 0; i < 2; ++i) {
      int id = (i << 4) + wave;
      int zq = id >> 2, yp = id & 3;
      int z = Z0 + zq;
#pragma unroll
      for (int r = 0; r < 4; ++r) {
        int m = (q << 2) + r;
        int yy2 = m >> 3, x2 = m & 7;
        int y = Y0 + (yp << 1) + yy2;
        int xx = X0 + x2;
        out[(((((b << 2) + n) * 32 + z) * 32 + y) * 32 + xx) << 3 | t8] =
            acc[i][r] + bias;
      }
    }
  }
}

extern "C" void kernel_launch(void* const* d_in, const int* in_sizes, int n_in,
                              void* d_out, int out_size, void* d_ws,
                              size_t ws_size, hipStream_t stream) {
  (void)in_sizes; (void)n_in; (void)out_size;
  const float* x = (const float*)d_in[0];
  const float* w1 = (const float*)d_in[1];
  const float* b1 = (const float*)d_in[2];
  const float* w2 = (const float*)d_in[3];
  const float* b2 = (const float*)d_in[4];
  const float* w3 = (const float*)d_in[5];
  const float* b3 = (const float*)d_in[6];
  float* out = (float*)d_out;
  float* part = (float*)d_ws;

  const size_t plane = (size_t)16 * 8 * 4096;  // floats per split (2 MB)
  int nsplit = 1;
  if (ws_size >= 4 * plane * 4 + 4096)
    nsplit = 4;
  else if (ws_size >= 2 * plane * 4 + 4096)
    nsplit = 2;
  unsigned* wtab = (unsigned*)(part + (size_t)nsplit * plane);

  switch (nsplit) {
    case 4:
      k_stage1<8><<<dim3(512), dim3(256), 0, stream>>>(x, w1, w3, part, wtab);
      k_stage23<4><<<dim3(1024), dim3(1024), 0, stream>>>(part, w2, b2, b3, b1,
                                                          w3, out);
      break;
    case 2:
      k_stage1<16><<<dim3(256), dim3(256), 0, stream>>>(x, w1, w3, part, wtab);
      k_stage23<2><<<dim3(1024), dim3(1024), 0, stream>>>(part, w2, b2, b3, b1,
                                                          w3, out);
      break;
    default:
      k_stage1<32><<<dim3(128), dim3(256), 0, stream>>>(x, w1, w3, part, wtab);
      k_stage23<1><<<dim3(1024), dim3(1024), 0, stream>>>(part, w2, b2, b3, b1,
                                                          w3, out);
      break;
  }
}